// Round 3
// baseline (17245.441 us; speedup 1.0000x reference)
//
#include <hip/hip_runtime.h>
#include <cmath>

#define EPSF 1e-8f
#define NINF (-__builtin_inff())

// Problem constants: B=1024 rows (x2 query sets), D=256 dims, S=65536 slots, K=16

__device__ __forceinline__ bool better(float v1, int i1, float v2, int i2) {
  // top-k order: larger value wins; tie -> smaller index (matches lax.top_k)
  return (v1 > v2) || (v1 == v2 && i1 < i2);
}

__device__ __forceinline__ float block_sum256(float x, float* red) {
  #pragma unroll
  for (int m = 1; m < 64; m <<= 1) x += __shfl_xor(x, m);
  __syncthreads();
  if ((threadIdx.x & 63) == 0) red[threadIdx.x >> 6] = x;
  __syncthreads();
  return red[0] + red[1] + red[2] + red[3];
}

// ---------------------------------------------------------------------------
// K0: per-slot address reciprocal norms: rdn[s] = 1/(||a_s|| + eps)
// ---------------------------------------------------------------------------
__global__ void addrnorm_kernel(const float* __restrict__ addr, float* __restrict__ rdn) {
  const int s = blockIdx.x * 4 + (threadIdx.x >> 6);
  const int lane = threadIdx.x & 63;
  const float4 a = *(const float4*)(addr + (size_t)s * 256 + lane * 4);
  float ss = a.x * a.x + a.y * a.y + a.z * a.z + a.w * a.w;
  #pragma unroll
  for (int m = 1; m < 64; m <<= 1) ss += __shfl_xor(ss, m);
  if (lane == 0) rdn[s] = 1.0f / (sqrtf(ss) + EPSF);
}

// ---------------------------------------------------------------------------
// K1: normalize key/value/query, circular-convolve (HRR bind), store
// ---------------------------------------------------------------------------
__global__ void prep_kernel(const float* __restrict__ key, const float* __restrict__ value,
                            const float* __restrict__ query, float* __restrict__ Qall,
                            float* __restrict__ qn1, float* __restrict__ bound) {
  const int b = blockIdx.x, t = threadIdx.x;
  __shared__ float kn[256], vn[256], red[4];
  const float kv = key[(size_t)b * 256 + t];
  const float vv = value[(size_t)b * 256 + t];
  const float qv = query[(size_t)b * 256 + t];
  const float sk = block_sum256(kv * kv, red);
  const float sv = block_sum256(vv * vv, red);
  const float sq = block_sum256(qv * qv, red);
  const float knv = kv / (sqrtf(sk) + EPSF);
  const float vnv = vv / (sqrtf(sv) + EPSF);
  const float qnv = qv / (sqrtf(sq) + EPSF);
  kn[t] = knv; vn[t] = vnv;
  qn1[(size_t)b * 256 + t] = qnv;
  // reference re-normalizes inside _topk_idx -> replicate double-normalize
  const float sk2 = block_sum256(knv * knv, red);
  const float sq2 = block_sum256(qnv * qnv, red);
  Qall[(size_t)b * 256 + t] = knv / (sqrtf(sk2) + EPSF);
  Qall[(size_t)(1024 + b) * 256 + t] = qnv / (sqrtf(sq2) + EPSF);
  __syncthreads();
  float acc = 0.f;
  for (int j = 0; j < 256; ++j) acc += kn[j] * vn[(t - j) & 255];
  bound[(size_t)b * 256 + t] = acc;
}

// ---------------------------------------------------------------------------
// Wave-collective bitonic sort of 32 buffered candidates -> keep sorted top-16
// in bV/bI[0..15]; returns new threshold (16th value). outV/outI: this lane's
// sorted entry (lanes 0..15 valid).
// ---------------------------------------------------------------------------
__device__ __noinline__ float flush32(float* bV, int* bI, int cnt,
                                      float& outV, int& outI) {
  const int lane = threadIdx.x & 63;
  const int l = lane & 31;
  float v = (l < cnt) ? bV[l] : NINF;
  int i = (l < cnt) ? bI[l] : 0x7FFFFFFF;
  #pragma unroll
  for (int k = 2; k <= 32; k <<= 1) {
    #pragma unroll
    for (int d = k >> 1; d >= 1; d >>= 1) {
      const float ov = __shfl_xor(v, d);
      const int oi = __shfl_xor(i, d);
      const bool desc = ((l & k) == 0);
      const bool low = ((l & d) == 0);
      const bool mb = better(v, i, ov, oi);
      const bool keep = desc ? (low ? mb : !mb) : (low ? !mb : mb);
      if (!keep) { v = ov; i = oi; }
    }
  }
  if (lane < 16) { bV[lane] = v; bI[lane] = i; }
  outV = v; outI = i;
  return __shfl(v, 15);
}

// ---------------------------------------------------------------------------
// Seed: full-wave bitonic sort-64 of (v,i); buffer <- top-16, returns 16th.
// ---------------------------------------------------------------------------
__device__ __noinline__ float seed16(float v, int i, float* bV, int* bI, int* cntp) {
  const int lane = threadIdx.x & 63;
  #pragma unroll
  for (int k = 2; k <= 64; k <<= 1) {
    #pragma unroll
    for (int d = k >> 1; d >= 1; d >>= 1) {
      const float ov = __shfl_xor(v, d);
      const int oi = __shfl_xor(i, d);
      const bool desc = ((lane & k) == 0);
      const bool low = ((lane & d) == 0);
      const bool mb = better(v, i, ov, oi);
      const bool keep = desc ? (low ? mb : !mb) : (low ? !mb : mb);
      if (!keep) { v = ov; i = oi; }
    }
  }
  if (lane < 16) { bV[lane] = v; bI[lane] = i; }
  if (lane == 0) *cntp = 16;
  return __shfl(v, 15);
}

// ---------------------------------------------------------------------------
// Rare path: append candidates (>= thr) to the row's LDS buffer via
// ballot/popc rank assignment; flush (sort-32 -> top-16) on overflow.
// ---------------------------------------------------------------------------
__device__ __noinline__ float heavy_append(float c0, float c1, float c2, float c3,
                                           int i0, int i1, int i2, int i3,
                                           float thr, float* bV, int* bI, int* cntp) {
  const int lane = threadIdx.x & 63;
  const unsigned long long ltmask = (1ull << lane) - 1ull;
  int cnt = *cntp;
  float cc[4] = {c0, c1, c2, c3};
  int ii[4] = {i0, i1, i2, i3};
  #pragma unroll
  for (int j = 0; j < 4; ++j) {
    bool f = (cc[j] >= thr);
    unsigned long long m = __ballot(f);
    while (m) {
      const int n = __popcll(m);
      const int freec = 32 - cnt;
      const int rk = __popcll(m & ltmask);
      if (n <= freec) {
        if (f) { bV[cnt + rk] = cc[j]; bI[cnt + rk] = ii[j]; }
        cnt += n;
        m = 0;
      } else {
        if (f && rk < freec) { bV[cnt + rk] = cc[j]; bI[cnt + rk] = ii[j]; f = false; }
        float dv; int di;
        thr = flush32(bV, bI, 32, dv, di);
        cnt = 16;
        f = f && (cc[j] >= thr);
        m = __ballot(f);
      }
    }
  }
  if (lane == 0) *cntp = cnt;
  return thr;
}

// ---------------------------------------------------------------------------
// Accumulate one 256-slot x 16-row block of dot products (64 float4 steps),
// ping-pong register prefetch on the address stream.
// ---------------------------------------------------------------------------
__device__ __forceinline__ void accum_iter(const float* __restrict__ ap,
                                           const float* __restrict__ Qs,
                                           float (&acc)[4][16]) {
  #pragma unroll
  for (int j = 0; j < 4; ++j)
    #pragma unroll
    for (int r = 0; r < 16; ++r) acc[j][r] = 0.f;

  float4 ca[4], cb[4];
  #define LOADJ(DST, D4) { _Pragma("unroll") for (int j = 0; j < 4; ++j) \
      DST[j] = *(const float4*)(ap + j * (64 * 256) + (D4) * 4); }
  #define FMABK(SRC, D4) { _Pragma("unroll") for (int r = 0; r < 16; ++r) { \
      const float4 q = *(const float4*)(Qs + r * 256 + (D4) * 4); \
      _Pragma("unroll") for (int j = 0; j < 4; ++j) \
        acc[j][r] += SRC[j].x * q.x + SRC[j].y * q.y + SRC[j].z * q.z + SRC[j].w * q.w; } }

  LOADJ(ca, 0)
  #pragma unroll 1
  for (int d4 = 0; d4 < 62; d4 += 2) {
    LOADJ(cb, d4 + 1)
    FMABK(ca, d4)
    LOADJ(ca, d4 + 2)
    FMABK(cb, d4 + 1)
  }
  LOADJ(cb, 63)
  FMABK(ca, 62)
  FMABK(cb, 63)
  #undef LOADJ
  #undef FMABK
}

// ---------------------------------------------------------------------------
// K2: similarities + seeded buffered exact top-16.
// Grid: 2048 = 16 chunks (4096 slots) x 128 row-tiles (16 rows), XCD-swizzled
// so each XCD streams one 4MB chunk (fits its private L2).
// Block: 256 thr = 4 waves; wave w owns slot quarter (1024 slots, 4 iters).
// Thread: 4 slots x 16 rows fp32 accumulators.
// ---------------------------------------------------------------------------
__launch_bounds__(256, 4)
__global__ void sims_topk_kernel(const float* __restrict__ Qall,
                                 const float* __restrict__ addr,
                                 const float* __restrict__ rdnG,
                                 float* __restrict__ pv, int* __restrict__ pi) {
  const int bx = blockIdx.x;
  const int xcd = bx & 7;
  const int s0 = bx >> 3;
  const int chunk = ((s0 >> 7) << 3) | xcd;  // 0..15
  const int rt = s0 & 127;                   // 0..127
  const int t = threadIdx.x;
  const int lane = t & 63;
  const int w = t >> 6;

  __shared__ float Q[16 * 256];       // 16 KB
  __shared__ float bufV[4][16][32];   // 8 KB
  __shared__ int   bufI[4][16][32];   // 8 KB
  __shared__ int   cnts[4][16];

  {
    const float4* src = (const float4*)(Qall + (size_t)(rt * 16) * 256);
    float4* dst = (float4*)Q;
    #pragma unroll
    for (int i = 0; i < 4; ++i) dst[i * 256 + t] = src[i * 256 + t];
  }
  __syncthreads();

  const int sbase0 = chunk * 4096 + w * 1024;
  float thrv[16];
  float acc[4][16];

  // ---- iter 0: accumulate + seed thresholds ----
  {
    const int sbase = sbase0;
    const float r0 = rdnG[sbase + lane];
    const float r1 = rdnG[sbase + 64 + lane];
    const float r2 = rdnG[sbase + 128 + lane];
    const float r3 = rdnG[sbase + 192 + lane];
    accum_iter(addr + (size_t)(sbase + lane) * 256, Q, acc);
    const int i0 = sbase + lane, i1 = i0 + 64, i2 = i0 + 128, i3 = i0 + 192;
    #pragma unroll
    for (int r = 0; r < 16; ++r) {
      float c0 = acc[0][r] * r0, c1 = acc[1][r] * r1, c2 = acc[2][r] * r2, c3 = acc[3][r] * r3;
      float bv = c0; int bi = i0; int mj = 0;
      if (better(c1, i1, bv, bi)) { bv = c1; bi = i1; mj = 1; }
      if (better(c2, i2, bv, bi)) { bv = c2; bi = i2; mj = 2; }
      if (better(c3, i3, bv, bi)) { bv = c3; bi = i3; mj = 3; }
      float th = seed16(bv, bi, &bufV[w][r][0], &bufI[w][r][0], &cnts[w][r]);
      c0 = (mj == 0) ? NINF : c0;
      c1 = (mj == 1) ? NINF : c1;
      c2 = (mj == 2) ? NINF : c2;
      c3 = (mj == 3) ? NINF : c3;
      const bool any = (c0 >= th) || (c1 >= th) || (c2 >= th) || (c3 >= th);
      if (__ballot(any) != 0ull)
        th = heavy_append(c0, c1, c2, c3, i0, i1, i2, i3, th,
                          &bufV[w][r][0], &bufI[w][r][0], &cnts[w][r]);
      thrv[r] = th;
    }
  }

  // ---- iters 1..3 ----
  #pragma unroll 1
  for (int it = 1; it < 4; ++it) {
    const int sbase = sbase0 + it * 256;
    const float r0 = rdnG[sbase + lane];
    const float r1 = rdnG[sbase + 64 + lane];
    const float r2 = rdnG[sbase + 128 + lane];
    const float r3 = rdnG[sbase + 192 + lane];
    accum_iter(addr + (size_t)(sbase + lane) * 256, Q, acc);
    const int i0 = sbase + lane, i1 = i0 + 64, i2 = i0 + 128, i3 = i0 + 192;
    #pragma unroll
    for (int r = 0; r < 16; ++r) {
      const float c0 = acc[0][r] * r0, c1 = acc[1][r] * r1, c2 = acc[2][r] * r2, c3 = acc[3][r] * r3;
      const float th = thrv[r];
      const bool any = (c0 >= th) || (c1 >= th) || (c2 >= th) || (c3 >= th);
      if (__ballot(any) != 0ull)
        thrv[r] = heavy_append(c0, c1, c2, c3, i0, i1, i2, i3, th,
                               &bufV[w][r][0], &bufI[w][r][0], &cnts[w][r]);
    }
  }

  // ---- final flush: per-wave sorted top-16 into buffer ----
  #pragma unroll 1
  for (int r = 0; r < 16; ++r) {
    float oV; int oI;
    flush32(&bufV[w][r][0], &bufI[w][r][0], cnts[w][r], oV, oI);
  }
  __syncthreads();
  // merge wave pairs (0<-1, 2<-3)
  if ((w & 1) == 0) {
    #pragma unroll 1
    for (int r = 0; r < 16; ++r) {
      if (lane < 16) {
        bufV[w][r][16 + lane] = bufV[w + 1][r][lane];
        bufI[w][r][16 + lane] = bufI[w + 1][r][lane];
      }
      float oV; int oI;
      flush32(&bufV[w][r][0], &bufI[w][r][0], 32, oV, oI);
    }
  }
  __syncthreads();
  // merge 0<-2, write block (row, chunk) top-16
  if (w == 0) {
    #pragma unroll 1
    for (int r = 0; r < 16; ++r) {
      if (lane < 16) {
        bufV[0][r][16 + lane] = bufV[2][r][lane];
        bufI[0][r][16 + lane] = bufI[2][r][lane];
      }
      float oV; int oI;
      flush32(&bufV[0][r][0], &bufI[0][r][0], 32, oV, oI);
      if (lane < 16) {
        const int grow = rt * 16 + r;
        pv[(size_t)grow * 256 + chunk * 16 + lane] = oV;
        pi[(size_t)grow * 256 + chunk * 16 + lane] = oI;
      }
    }
  }
}

// ---------------------------------------------------------------------------
// K3: merge 16 chunk-partials (256 candidates) -> final top-16 per row.
// ---------------------------------------------------------------------------
__global__ void merge_topk_kernel(const float* __restrict__ pv, const int* __restrict__ pi,
                                  int* __restrict__ fidx) {
  const int row = blockIdx.x;
  const int lane = threadIdx.x; // 64 threads
  float v[4]; int ix[4];
  #pragma unroll
  for (int j = 0; j < 4; ++j) {
    v[j] = pv[(size_t)row * 256 + j * 64 + lane];
    ix[j] = pi[(size_t)row * 256 + j * 64 + lane];
  }
  for (int s = 0; s < 16; ++s) {
    float bv = v[0]; int bi = ix[0];
    #pragma unroll
    for (int j = 1; j < 4; ++j) if (better(v[j], ix[j], bv, bi)) { bv = v[j]; bi = ix[j]; }
    #pragma unroll
    for (int m = 1; m < 64; m <<= 1) {
      const float ov = __shfl_xor(bv, m); const int oi = __shfl_xor(bi, m);
      if (better(ov, oi, bv, bi)) { bv = ov; bi = oi; }
    }
    if (lane == 0) fidx[(size_t)row * 16 + s] = bi;
    #pragma unroll
    for (int j = 0; j < 4; ++j) if (ix[j] == bi) v[j] = NINF; // ids unique
  }
}

// ---------------------------------------------------------------------------
// K4: content gather (decayed memory + write-hits via bitset join),
//     unbind via direct 256-pt DFT (Wiener division), normalize, store.
// ---------------------------------------------------------------------------
__global__ void finalize_kernel(const float* __restrict__ qn1,
                                const float* __restrict__ bound,
                                const int* __restrict__ fidx,
                                const float* __restrict__ mem,
                                float* __restrict__ out) {
  const int b = blockIdx.x, t = threadIdx.x;
  __shared__ unsigned int bs[2048];   // 65536-bit slot bitset
  __shared__ float cont[256], qn[256];
  __shared__ float Br[129], Bi[129];
  __shared__ float2 tw[256];
  __shared__ int ri[16];
  __shared__ int hits[1024];
  __shared__ int hcnt;
  __shared__ float red[4];

  {
    const double ang = (6.283185307179586476925286766559 / 256.0) * (double)t;
    tw[t] = make_float2((float)cos(ang), (float)sin(ang));
  }
  #pragma unroll
  for (int i = 0; i < 8; ++i) bs[t + i * 256] = 0u;
  if (t == 0) hcnt = 0;
  qn[t] = qn1[(size_t)b * 256 + t];
  if (t < 16) ri[t] = fidx[(size_t)(1024 + b) * 16 + t]; // read slots
  __syncthreads();
  if (t < 16) atomicOr(&bs[ri[t] >> 5], 1u << (ri[t] & 31));
  __syncthreads();

  float c = 0.f;
  #pragma unroll
  for (int k = 0; k < 16; ++k) c += mem[(size_t)ri[k] * 256 + t];
  c *= 0.995f;

  for (int e = t; e < 16384; e += 256) {
    const int s = fidx[e]; // rows 0..1023 of fidx = idx_w
    if ((bs[s >> 5] >> (s & 31)) & 1u) {
      const int p = atomicAdd(&hcnt, 1);
      if (p < 1024) hits[p] = e;
    }
  }
  __syncthreads();
  int hn = hcnt; if (hn > 1024) hn = 1024;
  if (t == 0) {
    for (int i = 1; i < hn; ++i) {
      const int x = hits[i]; int j2 = i - 1;
      while (j2 >= 0 && hits[j2] > x) { hits[j2 + 1] = hits[j2]; --j2; }
      hits[j2 + 1] = x;
    }
  }
  __syncthreads();
  for (int h = 0; h < hn; ++h) c += bound[(size_t)(hits[h] >> 4) * 256 + t];
  cont[t] = c;
  __syncthreads();

  if (t < 129) {
    float ar = 0.f, ai = 0.f, cr2 = 0.f, ci2 = 0.f;
    for (int n = 0; n < 256; ++n) {
      const float2 wv = tw[(t * n) & 255];
      const float qv = qn[n], cv = cont[n];
      ar += qv * wv.x; ai -= qv * wv.y;
      cr2 += cv * wv.x; ci2 -= cv * wv.y;
    }
    const float den = ar * ar + ai * ai + 1e-8f;
    Br[t] = (cr2 * ar + ci2 * ai) / den;
    Bi[t] = (ci2 * ar - cr2 * ai) / den;
  }
  __syncthreads();

  float o = Br[0] + ((t & 1) ? -Br[128] : Br[128]);
  for (int k = 1; k < 128; ++k) {
    const float2 wv = tw[(k * t) & 255];
    o += 2.f * (Br[k] * wv.x - Bi[k] * wv.y);
  }
  o *= (1.f / 256.f);

  const float ss2 = block_sum256(o * o, red);
  out[(size_t)b * 256 + t] = o / (sqrtf(ss2) + EPSF);
}

// ---------------------------------------------------------------------------
extern "C" void kernel_launch(void* const* d_in, const int* in_sizes, int n_in,
                              void* d_out, int out_size, void* d_ws, size_t ws_size,
                              hipStream_t stream) {
  const float* key    = (const float*)d_in[0];
  const float* value  = (const float*)d_in[1];
  const float* query  = (const float*)d_in[2];
  const float* addr   = (const float*)d_in[3];
  const float* memory = (const float*)d_in[4];
  float* out = (float*)d_out;

  char* ws = (char*)d_ws;
  float* Qall  = (float*)(ws + 0);                       // 2 MB
  float* qn1   = (float*)(ws + (2u << 20));              // 1 MB
  float* bound = (float*)(ws + (3u << 20));              // 1 MB
  float* pv    = (float*)(ws + (4u << 20));              // 2048*256*4 = 2 MB
  int*   pi    = (int*)  (ws + (6u << 20));              // 2 MB
  int*   fidx  = (int*)  (ws + (8u << 20));              // 128 KB
  float* rdn   = (float*)(ws + (8u << 20) + (128u << 10)); // 256 KB

  addrnorm_kernel<<<16384, 256, 0, stream>>>(addr, rdn);
  prep_kernel<<<1024, 256, 0, stream>>>(key, value, query, Qall, qn1, bound);
  sims_topk_kernel<<<2048, 256, 0, stream>>>(Qall, addr, rdn, pv, pi);
  merge_topk_kernel<<<2048, 64, 0, stream>>>(pv, pi, fidx);
  finalize_kernel<<<1024, 256, 0, stream>>>(qn1, bound, fidx, memory, out);
}

// Round 4
// 3015.756 us; speedup vs baseline: 5.7184x; 5.7184x over previous
//
#include <hip/hip_runtime.h>
#include <cmath>

#define EPSF 1e-8f
#define NINF (-__builtin_inff())

typedef float v2f __attribute__((ext_vector_type(2)));

// Problem constants: B=1024 rows (x2 query sets), D=256 dims, S=65536 slots, K=16

__device__ __forceinline__ bool better(float v1, int i1, float v2, int i2) {
  // top-k order: larger value wins; tie -> smaller index (matches lax.top_k)
  return (v1 > v2) || (v1 == v2 && i1 < i2);
}

__device__ __forceinline__ float block_sum256(float x, float* red) {
  #pragma unroll
  for (int m = 1; m < 64; m <<= 1) x += __shfl_xor(x, m);
  __syncthreads();
  if ((threadIdx.x & 63) == 0) red[threadIdx.x >> 6] = x;
  __syncthreads();
  return red[0] + red[1] + red[2] + red[3];
}

// ---------------------------------------------------------------------------
// K0: per-slot address reciprocal norms: rdn[s] = 1/(||a_s|| + eps)
// ---------------------------------------------------------------------------
__global__ void addrnorm_kernel(const float* __restrict__ addr, float* __restrict__ rdn) {
  const int s = blockIdx.x * 4 + (threadIdx.x >> 6);
  const int lane = threadIdx.x & 63;
  const float4 a = *(const float4*)(addr + (size_t)s * 256 + lane * 4);
  float ss = a.x * a.x + a.y * a.y + a.z * a.z + a.w * a.w;
  #pragma unroll
  for (int m = 1; m < 64; m <<= 1) ss += __shfl_xor(ss, m);
  if (lane == 0) rdn[s] = 1.0f / (sqrtf(ss) + EPSF);
}

// ---------------------------------------------------------------------------
// K1: normalize key/value/query, circular-convolve (HRR bind), store
// ---------------------------------------------------------------------------
__global__ void prep_kernel(const float* __restrict__ key, const float* __restrict__ value,
                            const float* __restrict__ query, float* __restrict__ Qall,
                            float* __restrict__ qn1, float* __restrict__ bound) {
  const int b = blockIdx.x, t = threadIdx.x;
  __shared__ float kn[256], vn[256], red[4];
  const float kv = key[(size_t)b * 256 + t];
  const float vv = value[(size_t)b * 256 + t];
  const float qv = query[(size_t)b * 256 + t];
  const float sk = block_sum256(kv * kv, red);
  const float sv = block_sum256(vv * vv, red);
  const float sq = block_sum256(qv * qv, red);
  const float knv = kv / (sqrtf(sk) + EPSF);
  const float vnv = vv / (sqrtf(sv) + EPSF);
  const float qnv = qv / (sqrtf(sq) + EPSF);
  kn[t] = knv; vn[t] = vnv;
  qn1[(size_t)b * 256 + t] = qnv;
  // reference re-normalizes inside _topk_idx -> replicate double-normalize
  const float sk2 = block_sum256(knv * knv, red);
  const float sq2 = block_sum256(qnv * qnv, red);
  Qall[(size_t)b * 256 + t] = knv / (sqrtf(sk2) + EPSF);
  Qall[(size_t)(1024 + b) * 256 + t] = qnv / (sqrtf(sq2) + EPSF);
  __syncthreads();
  float acc = 0.f;
  for (int j = 0; j < 256; ++j) acc += kn[j] * vn[(t - j) & 255];
  bound[(size_t)b * 256 + t] = acc;
}

// ---------------------------------------------------------------------------
// Wave-collective bitonic sort of 32 buffered candidates -> keep sorted top-16
// in bV/bI[0..15]; returns new threshold (16th value). outV/outI: this lane's
// sorted entry (lanes 0..15 valid).
// ---------------------------------------------------------------------------
__device__ __noinline__ float flush32(float* bV, int* bI, int cnt,
                                      float& outV, int& outI) {
  const int lane = threadIdx.x & 63;
  const int l = lane & 31;
  float v = (l < cnt) ? bV[l] : NINF;
  int i = (l < cnt) ? bI[l] : 0x7FFFFFFF;
  #pragma unroll
  for (int k = 2; k <= 32; k <<= 1) {
    #pragma unroll
    for (int d = k >> 1; d >= 1; d >>= 1) {
      const float ov = __shfl_xor(v, d);
      const int oi = __shfl_xor(i, d);
      const bool desc = ((l & k) == 0);
      const bool low = ((l & d) == 0);
      const bool mb = better(v, i, ov, oi);
      const bool keep = desc ? (low ? mb : !mb) : (low ? !mb : mb);
      if (!keep) { v = ov; i = oi; }
    }
  }
  if (lane < 16) { bV[lane] = v; bI[lane] = i; }
  outV = v; outI = i;
  return __shfl(v, 15);
}

// ---------------------------------------------------------------------------
// Seed: full-wave bitonic sort-64 of (v,i); buffer <- top-16, returns 16th.
// ---------------------------------------------------------------------------
__device__ __noinline__ float seed16(float v, int i, float* bV, int* bI, int* cntp) {
  const int lane = threadIdx.x & 63;
  #pragma unroll
  for (int k = 2; k <= 64; k <<= 1) {
    #pragma unroll
    for (int d = k >> 1; d >= 1; d >>= 1) {
      const float ov = __shfl_xor(v, d);
      const int oi = __shfl_xor(i, d);
      const bool desc = ((lane & k) == 0);
      const bool low = ((lane & d) == 0);
      const bool mb = better(v, i, ov, oi);
      const bool keep = desc ? (low ? mb : !mb) : (low ? !mb : mb);
      if (!keep) { v = ov; i = oi; }
    }
  }
  if (lane < 16) { bV[lane] = v; bI[lane] = i; }
  if (lane == 0) *cntp = 16;
  return __shfl(v, 15);
}

// ---------------------------------------------------------------------------
// Rare path: append candidates (>= thr) to the row's LDS buffer via
// ballot/popc rank assignment; flush (sort-32 -> top-16) on overflow.
// ---------------------------------------------------------------------------
__device__ __noinline__ float heavy_append(float c0, float c1, float c2, float c3,
                                           int i0, int i1, int i2, int i3,
                                           float thr, float* bV, int* bI, int* cntp) {
  const int lane = threadIdx.x & 63;
  const unsigned long long ltmask = (1ull << lane) - 1ull;
  int cnt = *cntp;
  float cc[4] = {c0, c1, c2, c3};
  int ii[4] = {i0, i1, i2, i3};
  #pragma unroll
  for (int j = 0; j < 4; ++j) {
    bool f = (cc[j] >= thr);
    unsigned long long m = __ballot(f);
    while (m) {
      const int n = __popcll(m);
      const int freec = 32 - cnt;
      const int rk = __popcll(m & ltmask);
      if (n <= freec) {
        if (f) { bV[cnt + rk] = cc[j]; bI[cnt + rk] = ii[j]; }
        cnt += n;
        m = 0;
      } else {
        if (f && rk < freec) { bV[cnt + rk] = cc[j]; bI[cnt + rk] = ii[j]; f = false; }
        float dv; int di;
        thr = flush32(bV, bI, 32, dv, di);
        cnt = 16;
        f = f && (cc[j] >= thr);
        m = __ballot(f);
      }
    }
  }
  if (lane == 0) *cntp = cnt;
  return thr;
}

// ---------------------------------------------------------------------------
// Accumulate one 256-slot x 8-row block of dot products; acc held as v2f
// (packed-f32 pairs; horizontal add deferred) to enable v_pk_fma_f32.
// ---------------------------------------------------------------------------
__device__ __forceinline__ void accum_iter8(const float* __restrict__ ap,
                                            const float* __restrict__ Qs,
                                            v2f (&acc)[4][8]) {
  #pragma unroll
  for (int j = 0; j < 4; ++j)
    #pragma unroll
    for (int r = 0; r < 8; ++r) acc[j][r] = (v2f)(0.f);

  #pragma unroll 2
  for (int d4 = 0; d4 < 64; ++d4) {
    float4 a[4];
    #pragma unroll
    for (int j = 0; j < 4; ++j) a[j] = *(const float4*)(ap + j * (64 * 256) + d4 * 4);
    #pragma unroll
    for (int r = 0; r < 8; ++r) {
      const float4 q = *(const float4*)(Qs + r * 256 + d4 * 4);
      const v2f qlo = {q.x, q.y};
      const v2f qhi = {q.z, q.w};
      #pragma unroll
      for (int j = 0; j < 4; ++j) {
        const v2f alo = {a[j].x, a[j].y};
        const v2f ahi = {a[j].z, a[j].w};
        acc[j][r] += alo * qlo;
        acc[j][r] += ahi * qhi;
      }
    }
  }
}

// ---------------------------------------------------------------------------
// K2: similarities + seeded buffered exact top-16.
// Grid: 2048 = 16 chunks (4096 slots) x 128 row-tiles (16 rows), XCD-swizzled
// so each XCD streams one 4MB chunk (fits its private L2).
// Block: 256 thr = 4 waves. Wave w: rows (w>>1)*8.., slot half (w&1)*2048.
// Thread: 4 slots x 8 rows packed-f32 accumulators.
// ---------------------------------------------------------------------------
__launch_bounds__(256)
__global__ void sims_topk_kernel(const float* __restrict__ Qall,
                                 const float* __restrict__ addr,
                                 const float* __restrict__ rdnG,
                                 float* __restrict__ pv, int* __restrict__ pi) {
  const int bx = blockIdx.x;
  const int xcd = bx & 7;
  const int s0 = bx >> 3;
  const int chunk = ((s0 >> 7) << 3) | xcd;  // 0..15
  const int rt = s0 & 127;                   // 0..127
  const int t = threadIdx.x;
  const int lane = t & 63;
  const int w = t >> 6;
  const int rg = w >> 1;        // row group (8 rows)
  const int sh = w & 1;         // slot half (2048 slots)

  __shared__ float Q[16 * 256];      // 16 KB
  __shared__ float bufV[4][8][32];   // 4 KB
  __shared__ int   bufI[4][8][32];   // 4 KB
  __shared__ int   cnts[4][8];

  {
    const float4* src = (const float4*)(Qall + (size_t)(rt * 16) * 256);
    float4* dst = (float4*)Q;
    #pragma unroll
    for (int i = 0; i < 4; ++i) dst[i * 256 + t] = src[i * 256 + t];
  }
  __syncthreads();

  const int sbase0 = chunk * 4096 + sh * 2048;
  const float* Qs = Q + rg * 8 * 256;
  float thrv[8];
  v2f acc[4][8];

  // ---- iter 0: accumulate + seed thresholds via sort-64 of lane-best ----
  {
    const int sbase = sbase0;
    const float r0 = rdnG[sbase + lane];
    const float r1 = rdnG[sbase + 64 + lane];
    const float r2 = rdnG[sbase + 128 + lane];
    const float r3 = rdnG[sbase + 192 + lane];
    accum_iter8(addr + (size_t)(sbase + lane) * 256, Qs, acc);
    const int i0 = sbase + lane, i1 = i0 + 64, i2 = i0 + 128, i3 = i0 + 192;
    #pragma unroll
    for (int r = 0; r < 8; ++r) {
      float c0 = (acc[0][r].x + acc[0][r].y) * r0;
      float c1 = (acc[1][r].x + acc[1][r].y) * r1;
      float c2 = (acc[2][r].x + acc[2][r].y) * r2;
      float c3 = (acc[3][r].x + acc[3][r].y) * r3;
      float bv = c0; int bi = i0; int mj = 0;
      if (better(c1, i1, bv, bi)) { bv = c1; bi = i1; mj = 1; }
      if (better(c2, i2, bv, bi)) { bv = c2; bi = i2; mj = 2; }
      if (better(c3, i3, bv, bi)) { bv = c3; bi = i3; mj = 3; }
      float th = seed16(bv, bi, &bufV[w][r][0], &bufI[w][r][0], &cnts[w][r]);
      c0 = (mj == 0) ? NINF : c0;
      c1 = (mj == 1) ? NINF : c1;
      c2 = (mj == 2) ? NINF : c2;
      c3 = (mj == 3) ? NINF : c3;
      const bool any = (c0 >= th) || (c1 >= th) || (c2 >= th) || (c3 >= th);
      if (__ballot(any) != 0ull)
        th = heavy_append(c0, c1, c2, c3, i0, i1, i2, i3, th,
                          &bufV[w][r][0], &bufI[w][r][0], &cnts[w][r]);
      thrv[r] = th;
    }
  }

  // ---- iters 1..7 ----
  #pragma unroll 1
  for (int it = 1; it < 8; ++it) {
    const int sbase = sbase0 + it * 256;
    const float r0 = rdnG[sbase + lane];
    const float r1 = rdnG[sbase + 64 + lane];
    const float r2 = rdnG[sbase + 128 + lane];
    const float r3 = rdnG[sbase + 192 + lane];
    accum_iter8(addr + (size_t)(sbase + lane) * 256, Qs, acc);
    const int i0 = sbase + lane, i1 = i0 + 64, i2 = i0 + 128, i3 = i0 + 192;
    #pragma unroll
    for (int r = 0; r < 8; ++r) {
      const float c0 = (acc[0][r].x + acc[0][r].y) * r0;
      const float c1 = (acc[1][r].x + acc[1][r].y) * r1;
      const float c2 = (acc[2][r].x + acc[2][r].y) * r2;
      const float c3 = (acc[3][r].x + acc[3][r].y) * r3;
      const float th = thrv[r];
      const bool any = (c0 >= th) || (c1 >= th) || (c2 >= th) || (c3 >= th);
      if (__ballot(any) != 0ull)
        thrv[r] = heavy_append(c0, c1, c2, c3, i0, i1, i2, i3, th,
                               &bufV[w][r][0], &bufI[w][r][0], &cnts[w][r]);
    }
  }

  // ---- final flush: per-wave sorted top-16 into buffer ----
  #pragma unroll 1
  for (int r = 0; r < 8; ++r) {
    float oV; int oI;
    flush32(&bufV[w][r][0], &bufI[w][r][0], cnts[w][r], oV, oI);
  }
  __syncthreads();
  // waves sh==0 merge partner wave's 16 -> exact chunk top-16, write out
  if (sh == 0) {
    #pragma unroll 1
    for (int r = 0; r < 8; ++r) {
      if (lane < 16) {
        bufV[w][r][16 + lane] = bufV[w + 1][r][lane];
        bufI[w][r][16 + lane] = bufI[w + 1][r][lane];
      }
      asm volatile("s_waitcnt lgkmcnt(0)" ::: "memory");
      float oV; int oI;
      flush32(&bufV[w][r][0], &bufI[w][r][0], 32, oV, oI);
      if (lane < 16) {
        const int grow = rt * 16 + rg * 8 + r;
        pv[(size_t)grow * 256 + chunk * 16 + lane] = oV;
        pi[(size_t)grow * 256 + chunk * 16 + lane] = oI;
      }
    }
  }
}

// ---------------------------------------------------------------------------
// K3: merge 16 chunk-partials (256 candidates) -> final top-16 per row.
// ---------------------------------------------------------------------------
__global__ void merge_topk_kernel(const float* __restrict__ pv, const int* __restrict__ pi,
                                  int* __restrict__ fidx) {
  const int row = blockIdx.x;
  const int lane = threadIdx.x; // 64 threads
  float v[4]; int ix[4];
  #pragma unroll
  for (int j = 0; j < 4; ++j) {
    v[j] = pv[(size_t)row * 256 + j * 64 + lane];
    ix[j] = pi[(size_t)row * 256 + j * 64 + lane];
  }
  for (int s = 0; s < 16; ++s) {
    float bv = v[0]; int bi = ix[0];
    #pragma unroll
    for (int j = 1; j < 4; ++j) if (better(v[j], ix[j], bv, bi)) { bv = v[j]; bi = ix[j]; }
    #pragma unroll
    for (int m = 1; m < 64; m <<= 1) {
      const float ov = __shfl_xor(bv, m); const int oi = __shfl_xor(bi, m);
      if (better(ov, oi, bv, bi)) { bv = ov; bi = oi; }
    }
    if (lane == 0) fidx[(size_t)row * 16 + s] = bi;
    #pragma unroll
    for (int j = 0; j < 4; ++j) if (ix[j] == bi) v[j] = NINF; // ids unique
  }
}

// ---------------------------------------------------------------------------
// K4: content gather (decayed memory + write-hits via bitset join),
//     unbind via direct 256-pt DFT (Wiener division), normalize, store.
// ---------------------------------------------------------------------------
__global__ void finalize_kernel(const float* __restrict__ qn1,
                                const float* __restrict__ bound,
                                const int* __restrict__ fidx,
                                const float* __restrict__ mem,
                                float* __restrict__ out) {
  const int b = blockIdx.x, t = threadIdx.x;
  __shared__ unsigned int bs[2048];   // 65536-bit slot bitset
  __shared__ float cont[256], qn[256];
  __shared__ float Br[129], Bi[129];
  __shared__ float2 tw[256];
  __shared__ int ri[16];
  __shared__ int hits[1024];
  __shared__ int hcnt;
  __shared__ float red[4];

  {
    const double ang = (6.283185307179586476925286766559 / 256.0) * (double)t;
    tw[t] = make_float2((float)cos(ang), (float)sin(ang));
  }
  #pragma unroll
  for (int i = 0; i < 8; ++i) bs[t + i * 256] = 0u;
  if (t == 0) hcnt = 0;
  qn[t] = qn1[(size_t)b * 256 + t];
  if (t < 16) ri[t] = fidx[(size_t)(1024 + b) * 16 + t]; // read slots
  __syncthreads();
  if (t < 16) atomicOr(&bs[ri[t] >> 5], 1u << (ri[t] & 31));
  __syncthreads();

  float c = 0.f;
  #pragma unroll
  for (int k = 0; k < 16; ++k) c += mem[(size_t)ri[k] * 256 + t];
  c *= 0.995f;

  for (int e = t; e < 16384; e += 256) {
    const int s = fidx[e]; // rows 0..1023 of fidx = idx_w
    if ((bs[s >> 5] >> (s & 31)) & 1u) {
      const int p = atomicAdd(&hcnt, 1);
      if (p < 1024) hits[p] = e;
    }
  }
  __syncthreads();
  int hn = hcnt; if (hn > 1024) hn = 1024;
  if (t == 0) {
    for (int i = 1; i < hn; ++i) {
      const int x = hits[i]; int j2 = i - 1;
      while (j2 >= 0 && hits[j2] > x) { hits[j2 + 1] = hits[j2]; --j2; }
      hits[j2 + 1] = x;
    }
  }
  __syncthreads();
  for (int h = 0; h < hn; ++h) c += bound[(size_t)(hits[h] >> 4) * 256 + t];
  cont[t] = c;
  __syncthreads();

  if (t < 129) {
    float ar = 0.f, ai = 0.f, cr2 = 0.f, ci2 = 0.f;
    for (int n = 0; n < 256; ++n) {
      const float2 wv = tw[(t * n) & 255];
      const float qv = qn[n], cv = cont[n];
      ar += qv * wv.x; ai -= qv * wv.y;
      cr2 += cv * wv.x; ci2 -= cv * wv.y;
    }
    const float den = ar * ar + ai * ai + 1e-8f;
    Br[t] = (cr2 * ar + ci2 * ai) / den;
    Bi[t] = (ci2 * ar - cr2 * ai) / den;
  }
  __syncthreads();

  float o = Br[0] + ((t & 1) ? -Br[128] : Br[128]);
  for (int k = 1; k < 128; ++k) {
    const float2 wv = tw[(k * t) & 255];
    o += 2.f * (Br[k] * wv.x - Bi[k] * wv.y);
  }
  o *= (1.f / 256.f);

  const float ss2 = block_sum256(o * o, red);
  out[(size_t)b * 256 + t] = o / (sqrtf(ss2) + EPSF);
}

// ---------------------------------------------------------------------------
extern "C" void kernel_launch(void* const* d_in, const int* in_sizes, int n_in,
                              void* d_out, int out_size, void* d_ws, size_t ws_size,
                              hipStream_t stream) {
  const float* key    = (const float*)d_in[0];
  const float* value  = (const float*)d_in[1];
  const float* query  = (const float*)d_in[2];
  const float* addr   = (const float*)d_in[3];
  const float* memory = (const float*)d_in[4];
  float* out = (float*)d_out;

  char* ws = (char*)d_ws;
  float* Qall  = (float*)(ws + 0);                       // 2 MB
  float* qn1   = (float*)(ws + (2u << 20));              // 1 MB
  float* bound = (float*)(ws + (3u << 20));              // 1 MB
  float* pv    = (float*)(ws + (4u << 20));              // 2048*256*4 = 2 MB
  int*   pi    = (int*)  (ws + (6u << 20));              // 2 MB
  int*   fidx  = (int*)  (ws + (8u << 20));              // 128 KB
  float* rdn   = (float*)(ws + (8u << 20) + (128u << 10)); // 256 KB

  addrnorm_kernel<<<16384, 256, 0, stream>>>(addr, rdn);
  prep_kernel<<<1024, 256, 0, stream>>>(key, value, query, Qall, qn1, bound);
  sims_topk_kernel<<<2048, 256, 0, stream>>>(Qall, addr, rdn, pv, pi);
  merge_topk_kernel<<<2048, 64, 0, stream>>>(pv, pi, fidx);
  finalize_kernel<<<1024, 256, 0, stream>>>(qn1, bound, fidx, memory, out);
}

// Round 5
// 2143.057 us; speedup vs baseline: 8.0471x; 1.4072x over previous
//
#include <hip/hip_runtime.h>
#include <cmath>

#define EPSF 1e-8f
#define NINF (-__builtin_inff())

typedef float f32x4 __attribute__((ext_vector_type(4)));
typedef short short8 __attribute__((ext_vector_type(8)));
typedef unsigned short ushort_t;

// Problem constants: B=1024 rows (x2 query sets), D=256 dims, S=65536 slots, K=16

__device__ __forceinline__ bool better(float v1, int i1, float v2, int i2) {
  // top-k order: larger value wins; tie -> smaller index (matches lax.top_k)
  return (v1 > v2) || (v1 == v2 && i1 < i2);
}

__device__ __forceinline__ float block_sum256(float x, float* red) {
  #pragma unroll
  for (int m = 1; m < 64; m <<= 1) x += __shfl_xor(x, m);
  __syncthreads();
  if ((threadIdx.x & 63) == 0) red[threadIdx.x >> 6] = x;
  __syncthreads();
  return red[0] + red[1] + red[2] + red[3];
}

__device__ __forceinline__ unsigned short f2bf(float x) {
  union { float f; unsigned int u; } c; c.f = x;
  unsigned int r = c.u + 0x7FFFu + ((c.u >> 16) & 1u);
  return (unsigned short)(r >> 16);
}

__device__ __forceinline__ void gload16(const ushort_t* g, ushort_t* l) {
  __builtin_amdgcn_global_load_lds(
      (const __attribute__((address_space(1))) unsigned int*)g,
      (__attribute__((address_space(3))) unsigned int*)l, 16, 0, 0);
}

// descending bitonic sort of 64 (v,i) pairs across the wave
__device__ __forceinline__ void sort64(float& v, int& i) {
  const int lane = threadIdx.x & 63;
  #pragma unroll
  for (int k = 2; k <= 64; k <<= 1) {
    #pragma unroll
    for (int d = k >> 1; d >= 1; d >>= 1) {
      const float ov = __shfl_xor(v, d);
      const int oi = __shfl_xor(i, d);
      const bool desc = ((lane & k) == 0);
      const bool low = ((lane & d) == 0);
      const bool mb = better(v, i, ov, oi);
      const bool keep = desc ? (low ? mb : !mb) : (low ? !mb : mb);
      if (!keep) { v = ov; i = oi; }
    }
  }
}

// ---------------------------------------------------------------------------
// K0: per-slot address reciprocal norms: rdn[s] = 1/(||a_s|| + eps)
// ---------------------------------------------------------------------------
__global__ void addrnorm_kernel(const float* __restrict__ addr, float* __restrict__ rdn) {
  const int s = blockIdx.x * 4 + (threadIdx.x >> 6);
  const int lane = threadIdx.x & 63;
  const float4 a = *(const float4*)(addr + (size_t)s * 256 + lane * 4);
  float ss = a.x * a.x + a.y * a.y + a.z * a.z + a.w * a.w;
  #pragma unroll
  for (int m = 1; m < 64; m <<= 1) ss += __shfl_xor(ss, m);
  if (lane == 0) rdn[s] = 1.0f / (sqrtf(ss) + EPSF);
}

// ---------------------------------------------------------------------------
// K0b: normalized addresses in bf16: abf[s][d] = bf16(addr[s][d] * rdn[s])
// ---------------------------------------------------------------------------
__global__ void anorm_bf_kernel(const float* __restrict__ addr, const float* __restrict__ rdn,
                                ushort_t* __restrict__ abf) {
  const int t = blockIdx.x * 256 + threadIdx.x;
  const size_t e0 = (size_t)t * 16;
  const int s = (int)(e0 >> 8);
  const float r = rdn[s];
  short8 o0, o1;
  #pragma unroll
  for (int k = 0; k < 2; ++k) {
    const float4 a = *(const float4*)(addr + e0 + k * 8);
    const float4 b = *(const float4*)(addr + e0 + k * 8 + 4);
    short8& o = k ? o1 : o0;
    o[0] = f2bf(a.x * r); o[1] = f2bf(a.y * r); o[2] = f2bf(a.z * r); o[3] = f2bf(a.w * r);
    o[4] = f2bf(b.x * r); o[5] = f2bf(b.y * r); o[6] = f2bf(b.z * r); o[7] = f2bf(b.w * r);
  }
  *(short8*)(abf + e0) = o0;
  *(short8*)(abf + e0 + 8) = o1;
}

// ---------------------------------------------------------------------------
// K1: normalize key/value/query, circular-convolve (HRR bind), store
// ---------------------------------------------------------------------------
__global__ void prep_kernel(const float* __restrict__ key, const float* __restrict__ value,
                            const float* __restrict__ query, float* __restrict__ Qall,
                            float* __restrict__ qn1, float* __restrict__ bound) {
  const int b = blockIdx.x, t = threadIdx.x;
  __shared__ float kn[256], vn[256], red[4];
  const float kv = key[(size_t)b * 256 + t];
  const float vv = value[(size_t)b * 256 + t];
  const float qv = query[(size_t)b * 256 + t];
  const float sk = block_sum256(kv * kv, red);
  const float sv = block_sum256(vv * vv, red);
  const float sq = block_sum256(qv * qv, red);
  const float knv = kv / (sqrtf(sk) + EPSF);
  const float vnv = vv / (sqrtf(sv) + EPSF);
  const float qnv = qv / (sqrtf(sq) + EPSF);
  kn[t] = knv; vn[t] = vnv;
  qn1[(size_t)b * 256 + t] = qnv;
  // reference re-normalizes inside _topk_idx -> replicate double-normalize
  const float sk2 = block_sum256(knv * knv, red);
  const float sq2 = block_sum256(qnv * qnv, red);
  Qall[(size_t)b * 256 + t] = knv / (sqrtf(sk2) + EPSF);
  Qall[(size_t)(1024 + b) * 256 + t] = qnv / (sqrtf(sq2) + EPSF);
  __syncthreads();
  float acc = 0.f;
  for (int j = 0; j < 256; ++j) acc += kn[j] * vn[(t - j) & 255];
  bound[(size_t)b * 256 + t] = acc;
}

// ---------------------------------------------------------------------------
// flush a 48-deep (row) candidate buffer: keep sorted top-24, return 24th val
// ---------------------------------------------------------------------------
__device__ __noinline__ float flush48(float* bV, int* bI, int cnt) {
  const int lane = threadIdx.x & 63;
  float v = (lane < cnt) ? bV[lane] : NINF;
  int i = (lane < cnt) ? bI[lane] : 0x7FFFFFFF;
  sort64(v, i);
  if (lane < 24) { bV[lane] = v; bI[lane] = i; }
  return __shfl(v, 23);
}

// ---------------------------------------------------------------------------
// append up to 4 candidates/lane (>= thr, idx!=INT_MAX) via ballot-rank;
// flush (keep top-24) on overflow. Returns possibly-raised threshold.
// ---------------------------------------------------------------------------
__device__ __noinline__ float append4(float c0, float c1, float c2, float c3,
                                      int i0, int i1, int i2, int i3,
                                      float thr, float* bV, int* bI, int* cntp) {
  const int lane = threadIdx.x & 63;
  const unsigned long long ltmask = (1ull << lane) - 1ull;
  int cnt = *cntp;
  float cc[4] = {c0, c1, c2, c3};
  int ii[4] = {i0, i1, i2, i3};
  #pragma unroll
  for (int j = 0; j < 4; ++j) {
    bool f = (cc[j] >= thr) && (ii[j] != 0x7FFFFFFF);
    unsigned long long m = __ballot(f);
    while (m) {
      const int n = __popcll(m);
      const int freec = 48 - cnt;
      const int rk = __popcll(m & ltmask);
      if (n <= freec) {
        if (f) { bV[cnt + rk] = cc[j]; bI[cnt + rk] = ii[j]; }
        cnt += n;
        m = 0;
      } else {
        if (f && rk < freec) { bV[cnt + rk] = cc[j]; bI[cnt + rk] = ii[j]; f = false; }
        thr = flush48(bV, bI, 48);
        cnt = 24;
        f = f && (cc[j] >= thr);
        m = __ballot(f);
      }
    }
  }
  if (lane == 0) *cntp = cnt;
  return thr;
}

// ---------------------------------------------------------------------------
// K2: bf16 MFMA sims + fused approx top-24 per (row, chunk).
// Grid: 1024 = 16 chunks x 64 q-tiles (XCD-swizzled: chunk pinned per XCD).
// Block: 256 thr = 4 waves (2 M-halves x 2 N-halves). q-tile 32 rows.
// Chunk 4096 slots: 16 subtiles x 256 slots; K=256 as 8 slices of 32.
// B staged via global_load_lds (dbuf, swizzled source); Q bf16 in LDS.
// ---------------------------------------------------------------------------
__global__ void gemm_scan_kernel(const float* __restrict__ Qall,
                                 const ushort_t* __restrict__ abf,
                                 float* __restrict__ pv, int* __restrict__ pi) {
  const int bx = blockIdx.x;
  const int xcd = bx & 7;
  const int idx = bx >> 3;          // 0..127
  const int chunk = xcd * 2 + (idx >> 6);
  const int qt = idx & 63;
  const int t = threadIdx.x;
  const int lane = t & 63;
  const int w = t >> 6;
  const int mhalf = w & 1;          // 16-row half
  const int nhalf = w >> 1;         // 128-slot half
  const int l15 = lane & 15, l4 = lane >> 4;

  __shared__ ushort_t Qlds[32 * 256];      // 16 KB (row stride 512B, swizzled granules)
  __shared__ ushort_t Blds[2][256 * 32];   // 2 x 16 KB ([slot][32 dims], swizzled)
  __shared__ float bufV[2][32][48];        // 12 KB
  __shared__ int   bufI[2][32][48];        // 12 KB
  __shared__ int   cnts[2][32];

  // ---- stage Q tile (f32 -> bf16, granule-swizzled: g ^= row&15) ----
  {
    const int row = t >> 3;
    const int dbase = (t & 7) * 32;
    const float* qsrc = Qall + ((size_t)qt * 32 + row) * 256 + dbase;
    #pragma unroll
    for (int gg = 0; gg < 4; ++gg) {
      const float4 a = *(const float4*)(qsrc + gg * 8);
      const float4 b = *(const float4*)(qsrc + gg * 8 + 4);
      short8 v;
      v[0] = f2bf(a.x); v[1] = f2bf(a.y); v[2] = f2bf(a.z); v[3] = f2bf(a.w);
      v[4] = f2bf(b.x); v[5] = f2bf(b.y); v[6] = f2bf(b.z); v[7] = f2bf(b.w);
      const int g = (t & 7) * 4 + gg;
      *(short8*)&Qlds[row * 256 + (g ^ (row & 15)) * 8] = v;
    }
    if (t < 64) cnts[t >> 5][t & 31] = 0;
  }

  // per-lane staging source offsets (ushort units), swizzle g^=(slot>>1)&3
  int inv[4];
  #pragma unroll
  for (int i = 0; i < 4; ++i) {
    const int sl = w * 64 + i * 16 + (lane >> 2);
    const int gs = (lane & 3) ^ ((sl >> 1) & 3);
    inv[i] = sl * 256 + gs * 8;
  }

  float thrv[16];
  #pragma unroll
  for (int r = 0; r < 16; ++r) thrv[r] = NINF;
  f32x4 acc[8];

  const size_t chunkbase = (size_t)chunk * 4096 * 256; // ushort units

  // ---- prologue: stage phase 0 ----
  {
    const size_t sb = chunkbase; // sub=0, ks=0
    #pragma unroll
    for (int i = 0; i < 4; ++i)
      gload16(abf + sb + inv[i], &Blds[0][w * 2048 + i * 512]);
  }
  asm volatile("s_waitcnt vmcnt(0)" ::: "memory");
  __syncthreads();

  // ---- 128 phases: (subtile 0..15) x (kslice 0..7) ----
  #pragma unroll 1
  for (int p = 0; p < 128; ++p) {
    const int sub = p >> 3, ks = p & 7;
    // stage next phase into other buffer
    if (p < 127) {
      const int pn = p + 1;
      const size_t sb = chunkbase + (size_t)(pn >> 3) * 256 * 256 + (size_t)(pn & 7) * 32;
      ushort_t* dst = &Blds[pn & 1][w * 2048];
      #pragma unroll
      for (int i = 0; i < 4; ++i)
        gload16(abf + sb + inv[i], dst + i * 512);
    }
    // compute current phase
    if (ks == 0) {
      #pragma unroll
      for (int ni = 0; ni < 8; ++ni) acc[ni] = (f32x4){0.f, 0.f, 0.f, 0.f};
    }
    const ushort_t* Bb = &Blds[p & 1][0];
    short8 af;
    {
      const int r = mhalf * 16 + l15;
      const int g = (ks * 4 + l4) ^ (r & 15);
      af = *(const short8*)&Qlds[r * 256 + g * 8];
    }
    short8 bfr[8];
    #pragma unroll
    for (int ni = 0; ni < 8; ++ni) {
      const int s = nhalf * 128 + ni * 16 + l15;
      const int g = l4 ^ ((s >> 1) & 3);
      bfr[ni] = *(const short8*)&Bb[s * 32 + g * 8];
    }
    #pragma unroll
    for (int ni = 0; ni < 8; ++ni)
      acc[ni] = __builtin_amdgcn_mfma_f32_16x16x32_bf16(af, bfr[ni], acc[ni], 0, 0, 0);

    // scan after last k-slice of the subtile
    if (ks == 7) {
      float rowmax[4];
      #pragma unroll
      for (int j = 0; j < 4; ++j) {
        float mx = acc[0][j];
        #pragma unroll
        for (int ni = 1; ni < 8; ++ni) mx = fmaxf(mx, acc[ni][j]);
        rowmax[j] = mx;
      }
      const int sbase = chunk * 4096 + sub * 256 + nhalf * 128;
      #pragma unroll
      for (int r = 0; r < 16; ++r) {
        const bool own = (l4 == (r >> 2));
        const bool hit = own && (rowmax[r & 3] >= thrv[r]);
        if (__ballot(hit) != 0ull) {
          float c[8]; int ci[8];
          #pragma unroll
          for (int ni = 0; ni < 8; ++ni) {
            c[ni] = own ? acc[ni][r & 3] : NINF;
            ci[ni] = own ? (sbase + ni * 16 + l15) : 0x7FFFFFFF;
          }
          const int row = mhalf * 16 + r;
          float* bV = &bufV[nhalf][row][0];
          int* bI = &bufI[nhalf][row][0];
          int* cp = &cnts[nhalf][row];
          float th = thrv[r];
          th = append4(c[0], c[1], c[2], c[3], ci[0], ci[1], ci[2], ci[3], th, bV, bI, cp);
          th = append4(c[4], c[5], c[6], c[7], ci[4], ci[5], ci[6], ci[7], th, bV, bI, cp);
          thrv[r] = th;
        }
      }
    }
    asm volatile("s_waitcnt vmcnt(0)" ::: "memory");
    __syncthreads();
  }

  // ---- final flush + N-half merge -> per (row, chunk) top-24 ----
  #pragma unroll 1
  for (int r = 0; r < 16; ++r) {
    const int row = mhalf * 16 + r;
    (void)flush48(&bufV[nhalf][row][0], &bufI[nhalf][row][0], cnts[nhalf][row]);
  }
  __syncthreads();
  if (nhalf == 0) {
    #pragma unroll 1
    for (int r = 0; r < 16; ++r) {
      const int row = mhalf * 16 + r;
      if (lane < 24) {
        bufV[0][row][24 + lane] = bufV[1][row][lane];
        bufI[0][row][24 + lane] = bufI[1][row][lane];
      }
      (void)flush48(&bufV[0][row][0], &bufI[0][row][0], 48);
      if (lane < 24) {
        const size_t grow = (size_t)qt * 32 + row;
        pv[grow * 384 + chunk * 24 + lane] = bufV[0][row][lane];
        pi[grow * 384 + chunk * 24 + lane] = bufI[0][row][lane];
      }
    }
  }
}

// ---------------------------------------------------------------------------
// K3: per row: sort 384 approx candidates, exact-fp32 rescore top-64,
//     exact top-16 indices -> fidx.
// ---------------------------------------------------------------------------
__global__ void merge_rescore_kernel(const float* __restrict__ pv, const int* __restrict__ pi,
                                     const float* __restrict__ Qall, const float* __restrict__ addr,
                                     const float* __restrict__ rdn, int* __restrict__ fidx) {
  const int row = blockIdx.x, t = threadIdx.x;
  __shared__ float sv[512];
  __shared__ int si[512];
  __shared__ float qrow[256];
  __shared__ float ps[64][4];

  for (int j = t; j < 512; j += 256) {
    sv[j] = (j < 384) ? pv[(size_t)row * 384 + j] : NINF;
    si[j] = (j < 384) ? pi[(size_t)row * 384 + j] : 0x7FFFFFFF;
  }
  qrow[t] = Qall[(size_t)row * 256 + t];
  __syncthreads();

  // block bitonic sort, descending by (val, idx)
  for (int k = 2; k <= 512; k <<= 1) {
    for (int j = k >> 1; j >= 1; j >>= 1) {
      const int i = ((t & ~(j - 1)) << 1) | (t & (j - 1));
      const int p = i | j;
      const bool up = ((i & k) == 0);
      const float vi = sv[i], vp = sv[p];
      const int ii = si[i], ip = si[p];
      const bool sw = up ? better(vp, ip, vi, ii) : better(vi, ii, vp, ip);
      if (sw) { sv[i] = vp; si[i] = ip; sv[p] = vi; si[p] = ii; }
      __syncthreads();
    }
  }

  // exact rescore of top-64 approx candidates
  const int c = t >> 2, part = t & 3;
  const int cidx = si[c];
  const bool valid = ((unsigned)cidx < 65536u);
  const int ix = valid ? cidx : 0;
  const float4* ap = (const float4*)(addr + (size_t)ix * 256 + part * 64);
  const float4* qp = (const float4*)(qrow + part * 64);
  float s = 0.f;
  #pragma unroll
  for (int k = 0; k < 16; ++k) {
    const float4 a = ap[k], q = qp[k];
    s += a.x * q.x + a.y * q.y + a.z * q.z + a.w * q.w;
  }
  ps[c][part] = s;
  __syncthreads();

  if (t < 64) {
    const int id2 = si[t];
    const bool v2 = ((unsigned)id2 < 65536u);
    const int ix2 = v2 ? id2 : 0;
    float ex = v2 ? (ps[t][0] + ps[t][1] + ps[t][2] + ps[t][3]) * rdn[ix2] : NINF;
    int id3 = v2 ? id2 : 0x7FFFFFFF;
    sort64(ex, id3);
    if (t < 16) fidx[(size_t)row * 16 + t] = id3;
  }
}

// ---------------------------------------------------------------------------
// K4: content gather (decayed memory + write-hits via bitset join),
//     unbind via direct 256-pt DFT (Wiener division), normalize, store.
// ---------------------------------------------------------------------------
__global__ void finalize_kernel(const float* __restrict__ qn1,
                                const float* __restrict__ bound,
                                const int* __restrict__ fidx,
                                const float* __restrict__ mem,
                                float* __restrict__ out) {
  const int b = blockIdx.x, t = threadIdx.x;
  __shared__ unsigned int bs[2048];   // 65536-bit slot bitset
  __shared__ float cont[256], qn[256];
  __shared__ float Br[129], Bi[129];
  __shared__ float2 tw[256];
  __shared__ int ri[16];
  __shared__ int hits[1024];
  __shared__ int hcnt;
  __shared__ float red[4];

  {
    const double ang = (6.283185307179586476925286766559 / 256.0) * (double)t;
    tw[t] = make_float2((float)cos(ang), (float)sin(ang));
  }
  #pragma unroll
  for (int i = 0; i < 8; ++i) bs[t + i * 256] = 0u;
  if (t == 0) hcnt = 0;
  qn[t] = qn1[(size_t)b * 256 + t];
  if (t < 16) ri[t] = fidx[(size_t)(1024 + b) * 16 + t]; // read slots
  __syncthreads();
  if (t < 16) atomicOr(&bs[ri[t] >> 5], 1u << (ri[t] & 31));
  __syncthreads();

  float c = 0.f;
  #pragma unroll
  for (int k = 0; k < 16; ++k) c += mem[(size_t)ri[k] * 256 + t];
  c *= 0.995f;

  for (int e = t; e < 16384; e += 256) {
    const int s = fidx[e]; // rows 0..1023 of fidx = idx_w
    if ((bs[s >> 5] >> (s & 31)) & 1u) {
      const int p = atomicAdd(&hcnt, 1);
      if (p < 1024) hits[p] = e;
    }
  }
  __syncthreads();
  int hn = hcnt; if (hn > 1024) hn = 1024;
  if (t == 0) {
    for (int i = 1; i < hn; ++i) {
      const int x = hits[i]; int j2 = i - 1;
      while (j2 >= 0 && hits[j2] > x) { hits[j2 + 1] = hits[j2]; --j2; }
      hits[j2 + 1] = x;
    }
  }
  __syncthreads();
  for (int h = 0; h < hn; ++h) c += bound[(size_t)(hits[h] >> 4) * 256 + t];
  cont[t] = c;
  __syncthreads();

  if (t < 129) {
    float ar = 0.f, ai = 0.f, cr2 = 0.f, ci2 = 0.f;
    for (int n = 0; n < 256; ++n) {
      const float2 wv = tw[(t * n) & 255];
      const float qv = qn[n], cv = cont[n];
      ar += qv * wv.x; ai -= qv * wv.y;
      cr2 += cv * wv.x; ci2 -= cv * wv.y;
    }
    const float den = ar * ar + ai * ai + 1e-8f;
    Br[t] = (cr2 * ar + ci2 * ai) / den;
    Bi[t] = (ci2 * ar - cr2 * ai) / den;
  }
  __syncthreads();

  float o = Br[0] + ((t & 1) ? -Br[128] : Br[128]);
  for (int k = 1; k < 128; ++k) {
    const float2 wv = tw[(k * t) & 255];
    o += 2.f * (Br[k] * wv.x - Bi[k] * wv.y);
  }
  o *= (1.f / 256.f);

  const float ss2 = block_sum256(o * o, red);
  out[(size_t)b * 256 + t] = o / (sqrtf(ss2) + EPSF);
}

// ---------------------------------------------------------------------------
extern "C" void kernel_launch(void* const* d_in, const int* in_sizes, int n_in,
                              void* d_out, int out_size, void* d_ws, size_t ws_size,
                              hipStream_t stream) {
  const float* key    = (const float*)d_in[0];
  const float* value  = (const float*)d_in[1];
  const float* query  = (const float*)d_in[2];
  const float* addr   = (const float*)d_in[3];
  const float* memory = (const float*)d_in[4];
  float* out = (float*)d_out;

  char* ws = (char*)d_ws;
  float*    Qall  = (float*)(ws + 0);                  // 2 MB
  float*    qn1   = (float*)(ws + (2ull << 20));       // 1 MB
  float*    bound = (float*)(ws + (3ull << 20));       // 1 MB
  float*    rdn   = (float*)(ws + (4ull << 20));       // 256 KB
  ushort_t* abf   = (ushort_t*)(ws + (5ull << 20));    // 32 MB
  float*    pv    = (float*)(ws + (37ull << 20));      // 3 MB (2048*384*4)
  int*      pi    = (int*)  (ws + (40ull << 20));      // 3 MB
  int*      fidx  = (int*)  (ws + (43ull << 20));      // 128 KB

  addrnorm_kernel<<<16384, 256, 0, stream>>>(addr, rdn);
  anorm_bf_kernel<<<4096, 256, 0, stream>>>(addr, rdn, abf);
  prep_kernel<<<1024, 256, 0, stream>>>(key, value, query, Qall, qn1, bound);
  gemm_scan_kernel<<<1024, 256, 0, stream>>>(Qall, abf, pv, pi);
  merge_rescore_kernel<<<2048, 256, 0, stream>>>(pv, pi, Qall, addr, rdn, fidx);
  finalize_kernel<<<1024, 256, 0, stream>>>(qn1, bound, fidx, memory, out);
}